// Round 7
// baseline (75.585 us; speedup 1.0000x reference)
//
#include <hip/hip_runtime.h>

#define HD __device__ __forceinline__

namespace {

constexpr int H = 1080, W = 1920, HW = H * W;
constexpr float FXc = 1000.0f, FYc = 1000.0f;
constexpr float D_COS = 0.867f, D_DIFF = 0.35f, D_Z = 0.05f, D_FARZ = 12.3f;
constexpr int NBH = 256;    // hist blocks
constexpr int NBINS = 8192; // bits>>18 for non-negative floats: 0 exp(8) man(5)

struct F3 { float x, y, z; };
HD F3 fsub(F3 a, F3 b) { return {a.x - b.x, a.y - b.y, a.z - b.z}; }
HD float fdot(F3 a, F3 b) { return a.x * b.x + a.y * b.y + a.z * b.z; }
HD F3 fcross(F3 a, F3 b) {
  return {a.y * b.z - a.z * b.y, a.z * b.x - a.x * b.z, a.x * b.y - a.y * b.x};
}

HD F3 mkpt2(float ux, float vy, float d) {
  float ad = fabsf(d);
  F3 p;
  p.x = ux * ad / FXc;
  p.y = vy * ad / FYc;
  p.z = d;
  return p;
}

HD F3 mkpt(int j, float d) {
  int v = j / W;
  int u = j - v * W;
  return mkpt2((float)(u - W / 2), (float)(v - H / 2), d);
}

// Core per-(group,batch) computation. Returns loss bits (0xFFFFFFFF if unmasked).
// cosine test via |dot| > D_COS*(na*nb+eps) (denominator > 0, exact vs division
// up to 1 ulp at the boundary); energy matrix is symmetric bitwise, so 3
// off-diagonal tests count double. Normals via 2 reciprocals.
HD unsigned vnl_elem(F3 A, F3 Bp, F3 C, F3 P0, F3 P1, F3 P2) {
  F3 e12 = fsub(Bp, A), e13 = fsub(C, A), e23 = fsub(C, Bp);
  float d00 = fdot(e12, e12), d11 = fdot(e13, e13), d22 = fdot(e23, e23);
  float n0 = sqrtf(d00), n1 = sqrtf(d11), n2 = sqrtf(d22);
  int cnt = 0;
  cnt += (d00 > D_COS * (n0 * n0 + 1e-8f)) ? 1 : 0;
  cnt += (d11 > D_COS * (n1 * n1 + 1e-8f)) ? 1 : 0;
  cnt += (d22 > D_COS * (n2 * n2 + 1e-8f)) ? 1 : 0;
  cnt += (fabsf(fdot(e12, e13)) > D_COS * (n0 * n1 + 1e-8f)) ? 2 : 0;
  cnt += (fabsf(fdot(e12, e23)) > D_COS * (n0 * n2 + 1e-8f)) ? 2 : 0;
  cnt += (fabsf(fdot(e13, e23)) > D_COS * (n1 * n2 + 1e-8f)) ? 2 : 0;
  bool mask_cos = cnt > 3;
  bool mask_pad = (A.z > D_Z) && (Bp.z > D_Z) && (C.z > D_Z);
  bool mask_far = (A.z < D_FARZ) && (Bp.z < D_FARZ) && (C.z < D_FARZ);
  bool mx = fabsf(e12.x) < D_DIFF || fabsf(e13.x) < D_DIFF || fabsf(e23.x) < D_DIFF;
  bool my = fabsf(e12.y) < D_DIFF || fabsf(e13.y) < D_DIFF || fabsf(e23.y) < D_DIFF;
  bool mz = fabsf(e12.z) < D_DIFF || fabsf(e13.z) < D_DIFF || fabsf(e23.z) < D_DIFF;
  bool masked = mask_pad && mask_far && !((mx && my && mz) || mask_cos);

  // reference's z_zero broadcast semantics:
  // if point c's z == 0, coordinate c of ALL points := 1e-4
  if (P0.z == 0.f) { P0.x = 1e-4f; P1.x = 1e-4f; P2.x = 1e-4f; }
  if (P1.z == 0.f) { P0.y = 1e-4f; P1.y = 1e-4f; P2.y = 1e-4f; }
  if (P2.z == 0.f) { P0.z = 1e-4f; P1.z = 1e-4f; P2.z = 1e-4f; }

  F3 ngt = fcross(e12, e13);
  float lg = sqrtf(fdot(ngt, ngt));
  lg += (lg == 0.f) ? 0.01f : 0.f;
  F3 q12 = fsub(P1, P0), q13 = fsub(P2, P0);
  F3 npr = fcross(q12, q13);
  float lp = sqrtf(fdot(npr, npr));
  lp += (lp == 0.f) ? 0.01f : 0.f;
  float ig = 1.0f / lg, ip = 1.0f / lp;
  float l = fabsf(ngt.x * ig - npr.x * ip) + fabsf(ngt.y * ig - npr.y * ip) +
            fabsf(ngt.z * ig - npr.z * ip);
  return masked ? __float_as_uint(l) : 0xFFFFFFFFu;
}

union PxU {
  uint4 u;
  _Float16 h[8];
};

// ---- packed fast path (B == 4): [HW] x {gt[0..3], pred[0..3]} fp16 = 16B/pixel ----
// Inputs read nontemporally (streamed once; keep L2 for pk gathers).
// Also zeroes the histogram buffers (folds the memset dispatch).
__global__ void vnl_pack(const float* __restrict__ pred, const float* __restrict__ gt,
                         uint4* __restrict__ pk, unsigned* __restrict__ hc,
                         float* __restrict__ hs) {
  int j = blockIdx.x * blockDim.x + threadIdx.x;
  if (j < NBINS) { hc[j] = 0u; hs[j] = 0.f; }
  if (j >= HW) return;
  PxU x;
  x.h[0] = (_Float16)__builtin_nontemporal_load(gt + j);
  x.h[1] = (_Float16)__builtin_nontemporal_load(gt + HW + j);
  x.h[2] = (_Float16)__builtin_nontemporal_load(gt + 2 * HW + j);
  x.h[3] = (_Float16)__builtin_nontemporal_load(gt + 3 * HW + j);
  x.h[4] = (_Float16)__builtin_nontemporal_load(pred + j);
  x.h[5] = (_Float16)__builtin_nontemporal_load(pred + HW + j);
  x.h[6] = (_Float16)__builtin_nontemporal_load(pred + 2 * HW + j);
  x.h[7] = (_Float16)__builtin_nontemporal_load(pred + 3 * HW + j);
  pk[j] = x.u;
}

// 1 group/thread, block=128 for maximal resident-wave concurrency.
__global__ void __launch_bounds__(128) vnl_main4(
    const uint4* __restrict__ pk, const int* __restrict__ p1,
    const int* __restrict__ p2, const int* __restrict__ p3,
    unsigned* __restrict__ ubits, int G) {
  int g = blockIdx.x * blockDim.x + threadIdx.x;
  if (g >= G) return;
  int j0 = p1[g], j1 = p2[g], j2 = p3[g];
  PxU x0, x1, x2;
  x0.u = pk[j0];
  x1.u = pk[j1];
  x2.u = pk[j2];
  int vr0 = j0 / W, vr1 = j1 / W, vr2 = j2 / W;
  float ux0 = (float)(j0 - vr0 * W - W / 2), vy0 = (float)(vr0 - H / 2);
  float ux1 = (float)(j1 - vr1 * W - W / 2), vy1 = (float)(vr1 - H / 2);
  float ux2 = (float)(j2 - vr2 * W - W / 2), vy2 = (float)(vr2 - H / 2);
#pragma unroll
  for (int b = 0; b < 4; ++b) {
    F3 A = mkpt2(ux0, vy0, (float)x0.h[b]);
    F3 Bp = mkpt2(ux1, vy1, (float)x1.h[b]);
    F3 C = mkpt2(ux2, vy2, (float)x2.h[b]);
    F3 P0 = mkpt2(ux0, vy0, (float)x0.h[4 + b]);
    F3 P1 = mkpt2(ux1, vy1, (float)x1.h[4 + b]);
    F3 P2 = mkpt2(ux2, vy2, (float)x2.h[4 + b]);
    // streamed, re-read once by vnl_hist: keep it out of L2
    __builtin_nontemporal_store(vnl_elem(A, Bp, C, P0, P1, P2), ubits + b * G + g);
  }
}

// ---- fallback scalar path (any B) ----
__global__ void vnl_main(const float* __restrict__ pred, const float* __restrict__ gt,
                         const int* __restrict__ p1, const int* __restrict__ p2,
                         const int* __restrict__ p3, unsigned* __restrict__ ubits,
                         int G, int N) {
  int i = blockIdx.x * blockDim.x + threadIdx.x;
  if (i >= N) return;
  int b = i / G;
  int g = i - b * G;
  int j1 = p1[g], j2 = p2[g], j3 = p3[g];
  const float* gb = gt + (size_t)b * HW;
  const float* pb = pred + (size_t)b * HW;
  ubits[i] = vnl_elem(mkpt(j1, gb[j1]), mkpt(j2, gb[j2]), mkpt(j3, gb[j3]),
                      mkpt(j1, pb[j1]), mkpt(j2, pb[j2]), mkpt(j3, pb[j3]));
}

// ---- per-bin {count,sum} histogram (8192 bins = bits>>18 for non-neg floats) ----
__global__ void vnl_hist(const unsigned* __restrict__ ubits, unsigned* __restrict__ hc,
                         float* __restrict__ hs, int N) {
  __shared__ unsigned cnt[NBINS];
  __shared__ float sum[NBINS];
  int tid = threadIdx.x;
  for (int i = tid; i < NBINS; i += 256) { cnt[i] = 0; sum[i] = 0.f; }
  __syncthreads();
  for (int i = blockIdx.x * 256 + tid; i < N; i += NBH * 256) {
    unsigned v = __builtin_nontemporal_load(ubits + i);
    if (v != 0xFFFFFFFFu) {
      atomicAdd(&cnt[v >> 18], 1u);
      atomicAdd(&sum[v >> 18], __uint_as_float(v));
    }
  }
  __syncthreads();
  for (int i = tid; i < NBINS; i += 256) {
    unsigned c = cnt[i];
    if (c) {
      atomicAdd(&hc[i], c);
      atomicAdd(&hs[i], sum[i]);
    }
  }
}

// single block, 1024 threads: scan 8192 bins, compute trimmed mean, write out.
__global__ void vnl_scanfinal(const unsigned* __restrict__ hc, const float* __restrict__ hs,
                              float* __restrict__ out) {
  __shared__ unsigned tsum[1024];
  __shared__ double dsum[1024];
  int tid = threadIdx.x;
  unsigned c8[8];
  float s8[8];
  unsigned s = 0;
  double d = 0.0;
#pragma unroll
  for (int jj = 0; jj < 8; ++jj) {
    c8[jj] = hc[tid * 8 + jj];
    s8[jj] = hs[tid * 8 + jj];
    s += c8[jj];
    d += (double)s8[jj];
  }
  tsum[tid] = s;
  dsum[tid] = d;
  __syncthreads();
  for (int off = 1; off < 1024; off <<= 1) {
    unsigned v = (tid >= off) ? tsum[tid - off] : 0u;
    double w = (tid >= off) ? dsum[tid - off] : 0.0;
    __syncthreads();
    tsum[tid] += v;
    dsum[tid] += w;
    __syncthreads();
  }
  unsigned V = tsum[1023];
  double S_all = dsum[1023];
  unsigned k = V >> 2;
  if (V == 0) {
    if (tid == 0) out[0] = 0.f;
    return;
  }
  if (k == 0) {
    if (tid == 0) out[0] = (float)(S_all / (double)V);
    return;
  }
  unsigned base = tsum[tid] - s;
  if (tsum[tid] >= k && base < k) {  // exactly one winner
    unsigned run = base;
    double acc = dsum[tid] - d;  // sum of all bins in earlier threads
#pragma unroll
    for (int jj = 0; jj < 8; ++jj) {
      unsigned c = c8[jj];
      if (run + c >= k) {
        unsigned bin = (unsigned)(tid * 8 + jj);
        double tmid = (double)__uint_as_float((bin << 18) | 0x20000u);
        double sum_keep = S_all - acc - (double)(k - run) * tmid;
        unsigned denom = V - k;
        if (denom < 1) denom = 1;
        out[0] = (float)(sum_keep / (double)denom);
        break;
      }
      run += c;
      acc += (double)s8[jj];
    }
  }
}

}  // namespace

extern "C" void kernel_launch(void* const* d_in, const int* in_sizes, int n_in,
                              void* d_out, int out_size, void* d_ws, size_t ws_size,
                              hipStream_t stream) {
  const float* pred = (const float*)d_in[0];
  const float* gt = (const float*)d_in[1];
  const int* p1 = (const int*)d_in[2];
  const int* p2 = (const int*)d_in[3];
  const int* p3 = (const int*)d_in[4];
  int B = in_sizes[0] / HW;
  int G = in_sizes[2];
  int N = B * G;

  char* ws = (char*)d_ws;
  size_t pk_bytes = (size_t)HW * 16;
  size_t ub_bytes = ((size_t)N * 4 + 255) & ~(size_t)255;
  size_t hist_bytes = (size_t)NBINS * 4;
  size_t need_fast = pk_bytes + ub_bytes + 2 * hist_bytes + 512;
  bool fast = (B == 4) && (ws_size >= need_fast);

  char* p = ws;
  uint4* pk = nullptr;
  if (fast) { pk = (uint4*)p; p += pk_bytes; }
  unsigned* ubits = (unsigned*)p; p += ub_bytes;
  unsigned* hc = (unsigned*)p; p += hist_bytes;
  float* hs = (float*)p;

  if (fast) {
    vnl_pack<<<(HW + 255) / 256, 256, 0, stream>>>(pred, gt, pk, hc, hs);
    vnl_main4<<<(G + 127) / 128, 128, 0, stream>>>(pk, p1, p2, p3, ubits, G);
  } else {
    hipMemsetAsync(hc, 0, 2 * hist_bytes, stream);
    vnl_main<<<(N + 255) / 256, 256, 0, stream>>>(pred, gt, p1, p2, p3, ubits, G, N);
  }
  vnl_hist<<<NBH, 256, 0, stream>>>(ubits, hc, hs, N);
  vnl_scanfinal<<<1, 1024, 0, stream>>>(hc, hs, (float*)d_out);
}